// Round 1
// baseline (410.130 us; speedup 1.0000x reference)
//
#include <hip/hip_runtime.h>

typedef unsigned short u16;
typedef __attribute__((ext_vector_type(4))) float f32x4;
typedef __attribute__((ext_vector_type(8))) short s16x8;
typedef __attribute__((ext_vector_type(4))) unsigned short u16x4;

// round-to-nearest-even f32 -> bf16
__device__ __forceinline__ u16 f2b(float x) {
  union { float f; unsigned u; } v; v.f = x;
  unsigned r = v.u + 0x7fffu + ((v.u >> 16) & 1u);
  return (u16)(r >> 16);
}

// ---------------- cast fp32 -> bf16, vectorized ----------------
__global__ __launch_bounds__(256) void cast_f32_bf16(const float* __restrict__ src,
                                                     u16* __restrict__ dst, int n4) {
  int i = blockIdx.x * 256 + threadIdx.x;
  if (i >= n4) return;
  float4 f = ((const float4*)src)[i];
  u16x4 o;
  o.x = f2b(f.x); o.y = f2b(f.y); o.z = f2b(f.z); o.w = f2b(f.w);
  ((u16x4*)dst)[i] = o;
}

// ---------------- W[E,A] fp32 -> Wt[A,E] bf16 ----------------
__global__ __launch_bounds__(256) void transpose_cast_w(const float* __restrict__ W,
                                                        u16* __restrict__ Wt, int E_, int A_) {
  __shared__ float tile[32][33];
  int a0 = blockIdx.x * 32, e0 = blockIdx.y * 32;
  int tx = threadIdx.x & 31, ty = threadIdx.x >> 5;
  for (int i = ty; i < 32; i += 8) tile[i][tx] = W[(long)(e0 + i) * A_ + a0 + tx];
  __syncthreads();
  for (int i = ty; i < 32; i += 8) Wt[(long)(a0 + i) * E_ + e0 + tx] = f2b(tile[tx][i]);
}

// ---------------- bf16 [rows,cols] -> [cols,rows], batched via grid.z ----------------
__global__ __launch_bounds__(256) void transpose_bf16(const u16* __restrict__ src,
                                                      u16* __restrict__ dst, int rows, int cols) {
  __shared__ u16 tile[32][33];
  long bo = (long)blockIdx.z * rows * cols;
  const u16* s = src + bo;
  u16* d = dst + bo;
  int c0 = blockIdx.x * 32, r0 = blockIdx.y * 32;
  int tx = threadIdx.x & 31, ty = threadIdx.x >> 5;
  for (int i = ty; i < 32; i += 8) tile[i][tx] = s[(long)(r0 + i) * cols + c0 + tx];
  __syncthreads();
  for (int i = ty; i < 32; i += 8) d[(long)(c0 + i) * rows + r0 + tx] = tile[tx][i];
}

// ---------------- bf16 MFMA GEMM: C[M,N] = A[M,K] * B[N,K]^T * scale + bias ----------------
// 128x128 tile, 4 waves of 64x64, BK=32, global_load_lds width=16 staging (m97 structure).
template<bool OUT_BF16>
__global__ __launch_bounds__(256)
void gemm_bt(const u16* __restrict__ Ag, const u16* __restrict__ Bg,
             const float* __restrict__ bias, void* __restrict__ Cg,
             int M, int N, int K, float scale, long sA, long sB, long sC) {
  __shared__ u16 As[128 * 32];
  __shared__ u16 Bs[128 * 32];
  const int t = threadIdx.x;
  const int wave = t >> 6, lane = t & 63;
  const int quad = lane >> 4, l16 = lane & 15;
  const int wm = wave & 1, wn = wave >> 1;
  const int m0 = blockIdx.y * 128, n0 = blockIdx.x * 128;
  const long zA = (long)blockIdx.z * sA;
  const long zB = (long)blockIdx.z * sB;
  const long zC = (long)blockIdx.z * sC;

  // staging: thread t loads 8 bf16 (16B); row = t/4, col = (t%4)*8; LDS dest byte = t*16
  const int ar = t >> 2, ac = (t & 3) * 8;
  const u16* Ap0 = Ag + zA + (long)(m0 + ar) * K + ac;
  const u16* Ap1 = Ag + zA + (long)(m0 + 64 + ar) * K + ac;
  const u16* Bp0 = Bg + zB + (long)(n0 + ar) * K + ac;
  const u16* Bp1 = Bg + zB + (long)(n0 + 64 + ar) * K + ac;
  u16* AsD0 = As + wave * 512;        // wave-uniform LDS bases (bytes: wave*1024)
  u16* AsD1 = As + 2048 + wave * 512; // second half-tile at byte 4096
  u16* BsD0 = Bs + wave * 512;
  u16* BsD1 = Bs + 2048 + wave * 512;

  f32x4 acc[4][4] = {};

  // fragment read base: A[m=l16][k=quad*8+j], row stride 32 elems
  const u16* Ard = As + (wm * 64 + l16) * 32 + quad * 8;
  const u16* Brd = Bs + (wn * 64 + l16) * 32 + quad * 8;

  for (int k0 = 0; k0 < K; k0 += 32) {
    __builtin_amdgcn_global_load_lds(
        (const __attribute__((address_space(1))) unsigned int*)(Ap0 + k0),
        (__attribute__((address_space(3))) unsigned int*)AsD0, 16, 0, 0);
    __builtin_amdgcn_global_load_lds(
        (const __attribute__((address_space(1))) unsigned int*)(Ap1 + k0),
        (__attribute__((address_space(3))) unsigned int*)AsD1, 16, 0, 0);
    __builtin_amdgcn_global_load_lds(
        (const __attribute__((address_space(1))) unsigned int*)(Bp0 + k0),
        (__attribute__((address_space(3))) unsigned int*)BsD0, 16, 0, 0);
    __builtin_amdgcn_global_load_lds(
        (const __attribute__((address_space(1))) unsigned int*)(Bp1 + k0),
        (__attribute__((address_space(3))) unsigned int*)BsD1, 16, 0, 0);
    __syncthreads();

    s16x8 fa[4], fb[4];
#pragma unroll
    for (int i = 0; i < 4; i++) fa[i] = *(const s16x8*)(Ard + i * 512);
#pragma unroll
    for (int j = 0; j < 4; j++) fb[j] = *(const s16x8*)(Brd + j * 512);
#pragma unroll
    for (int i = 0; i < 4; i++)
#pragma unroll
      for (int j = 0; j < 4; j++)
        acc[i][j] = __builtin_amdgcn_mfma_f32_16x16x32_bf16(fa[i], fb[j], acc[i][j], 0, 0, 0);
    __syncthreads();
  }

  float bj[4];
#pragma unroll
  for (int j = 0; j < 4; j++) {
    int col = n0 + wn * 64 + j * 16 + l16;
    bj[j] = bias ? bias[col] : 0.0f;
  }
  // C/D layout (16x16x32 bf16): col = lane&15, row = quad*4 + reg
#pragma unroll
  for (int i = 0; i < 4; i++) {
#pragma unroll
    for (int r = 0; r < 4; r++) {
      long row = m0 + wm * 64 + i * 16 + quad * 4 + r;
      long ro = zC + row * (long)N;
#pragma unroll
      for (int j = 0; j < 4; j++) {
        int col = n0 + wn * 64 + j * 16 + l16;
        float v = acc[i][j][r] * scale + bj[j];
        if (OUT_BF16) ((u16*)Cg)[ro + col] = f2b(v);
        else          ((float*)Cg)[ro + col] = v;
      }
    }
  }
}

// ---------------- row softmax: fp32 [rows,2048] -> bf16 probs ----------------
__device__ __forceinline__ float wred_max(float x) {
  for (int o = 32; o > 0; o >>= 1) x = fmaxf(x, __shfl_xor(x, o));
  return x;
}
__device__ __forceinline__ float wred_sum(float x) {
  for (int o = 32; o > 0; o >>= 1) x += __shfl_xor(x, o);
  return x;
}

__global__ __launch_bounds__(256) void softmax_rows(const float* __restrict__ S,
                                                    u16* __restrict__ P, int ncols) {
  long row = blockIdx.x;
  const float4* s4 = (const float4*)(S + row * (long)ncols);
  int t = threadIdx.x;
  int wave = t >> 6, lane = t & 63;
  float4 a = s4[t], b = s4[t + 256];
  float m = fmaxf(fmaxf(fmaxf(a.x, a.y), fmaxf(a.z, a.w)),
                  fmaxf(fmaxf(b.x, b.y), fmaxf(b.z, b.w)));
  m = wred_max(m);
  __shared__ float redm[4], reds[4];
  if (lane == 0) redm[wave] = m;
  __syncthreads();
  m = fmaxf(fmaxf(redm[0], redm[1]), fmaxf(redm[2], redm[3]));

  float e[8];
  e[0] = __expf(a.x - m); e[1] = __expf(a.y - m); e[2] = __expf(a.z - m); e[3] = __expf(a.w - m);
  e[4] = __expf(b.x - m); e[5] = __expf(b.y - m); e[6] = __expf(b.z - m); e[7] = __expf(b.w - m);
  float s = e[0] + e[1] + e[2] + e[3] + e[4] + e[5] + e[6] + e[7];
  s = wred_sum(s);
  if (lane == 0) reds[wave] = s;
  __syncthreads();
  s = reds[0] + reds[1] + reds[2] + reds[3];
  float inv = 1.0f / s;

  u16x4 o0, o1;
  o0.x = f2b(e[0] * inv); o0.y = f2b(e[1] * inv); o0.z = f2b(e[2] * inv); o0.w = f2b(e[3] * inv);
  o1.x = f2b(e[4] * inv); o1.y = f2b(e[5] * inv); o1.z = f2b(e[6] * inv); o1.w = f2b(e[7] * inv);
  u16x4* p4 = (u16x4*)(P + row * (long)ncols);
  p4[t] = o0;
  p4[t + 256] = o1;
}

extern "C" void kernel_launch(void* const* d_in, const int* in_sizes, int n_in,
                              void* d_out, int out_size, void* d_ws, size_t ws_size,
                              hipStream_t stream) {
  const float* query = (const float*)d_in[0];
  const float* key_  = (const float*)d_in[1];
  const float* value = (const float*)d_in[2];
  const float* Wq = (const float*)d_in[3];
  const float* bq = (const float*)d_in[4];
  const float* Wk = (const float*)d_in[5];
  const float* bk = (const float*)d_in[6];
  const float* Wv = (const float*)d_in[7];
  const float* bv = (const float*)d_in[8];

  constexpr int B = 4, S = 2048, E = 1024, A = 1024;
  constexpr long MB = 1024 * 1024;
  char* ws = (char*)d_ws;
  // layout (MiB): Qb 0-16, Kb 16-32, Vb 32-48, Vt 48-64, P 64-96, Sc 96-160.
  // transient casts (consumed before Sc written) overlap 96-150.
  u16* Qb  = (u16*)(ws + 0 * MB);
  u16* Kb  = (u16*)(ws + 16 * MB);
  u16* Vb  = (u16*)(ws + 32 * MB);
  u16* Vt  = (u16*)(ws + 48 * MB);
  u16* P   = (u16*)(ws + 64 * MB);
  float* Sc = (float*)(ws + 96 * MB);
  u16* Xq  = (u16*)(ws + 96 * MB);
  u16* Xk  = (u16*)(ws + 112 * MB);
  u16* Xv  = (u16*)(ws + 128 * MB);
  u16* WqT = (u16*)(ws + 144 * MB);
  u16* WkT = (u16*)(ws + 146 * MB);
  u16* WvT = (u16*)(ws + 148 * MB);

  const int n = B * S * E;           // 8M activation elements
  const int n4 = n / 4;
  dim3 blk(256);

  cast_f32_bf16<<<dim3(n4 / 256), blk, 0, stream>>>(query, Xq, n4);
  cast_f32_bf16<<<dim3(n4 / 256), blk, 0, stream>>>(key_,  Xk, n4);
  cast_f32_bf16<<<dim3(n4 / 256), blk, 0, stream>>>(value, Xv, n4);

  transpose_cast_w<<<dim3(A / 32, E / 32), blk, 0, stream>>>(Wq, WqT, E, A);
  transpose_cast_w<<<dim3(A / 32, E / 32), blk, 0, stream>>>(Wk, WkT, E, A);
  transpose_cast_w<<<dim3(A / 32, E / 32), blk, 0, stream>>>(Wv, WvT, E, A);

  // projections: [8192,1024] x [1024,1024]^T  -> bf16 Q/K/V
  dim3 pg(A / 128, (B * S) / 128, 1);
  gemm_bt<true><<<pg, blk, 0, stream>>>(Xq, WqT, bq, Qb, B * S, A, E, 1.0f, 0, 0, 0);
  gemm_bt<true><<<pg, blk, 0, stream>>>(Xk, WkT, bk, Kb, B * S, A, E, 1.0f, 0, 0, 0);
  gemm_bt<true><<<pg, blk, 0, stream>>>(Xv, WvT, bv, Vb, B * S, A, E, 1.0f, 0, 0, 0);

  // V^T for the PV gemm_bt
  transpose_bf16<<<dim3(A / 32, S / 32, B), blk, 0, stream>>>(Vb, Vt, S, A);

  // scores = Q K^T / sqrt(A), fp32, batched over B (overwrites cast region)
  dim3 sg(S / 128, S / 128, B);
  gemm_bt<false><<<sg, blk, 0, stream>>>(Qb, Kb, nullptr, Sc, S, S, A, 0.03125f,
                                         (long)S * A, (long)S * A, (long)S * S);

  softmax_rows<<<dim3(B * S), blk, 0, stream>>>(Sc, P, S);

  // out = P V : A=P[S,S], B=Vt[A,S] -> fp32 d_out
  dim3 og(A / 128, S / 128, B);
  gemm_bt<false><<<og, blk, 0, stream>>>(P, Vt, nullptr, (float*)d_out, S, A, S, 1.0f,
                                         (long)S * S, (long)S * A, (long)S * A);
}

// Round 2
// 373.276 us; speedup vs baseline: 1.0987x; 1.0987x over previous
//
#include <hip/hip_runtime.h>

typedef unsigned short u16;
typedef __attribute__((ext_vector_type(4))) float f32x4;
typedef __attribute__((ext_vector_type(8))) short s16x8;
typedef __attribute__((ext_vector_type(8))) unsigned short u16x8;
typedef __attribute__((ext_vector_type(4))) unsigned short u16x4;

// round-to-nearest-even f32 -> bf16
__device__ __forceinline__ u16 f2b(float x) {
  union { float f; unsigned u; } v; v.f = x;
  unsigned r = v.u + 0x7fffu + ((v.u >> 16) & 1u);
  return (u16)(r >> 16);
}
__device__ __forceinline__ float b2f(u16 x) {
  union { unsigned u; float f; } v; v.u = ((unsigned)x) << 16;
  return v.f;
}

// ---------------- cast fp32 -> bf16, 3 inputs in one launch (grid.y selects) ----------------
__global__ __launch_bounds__(256) void cast3_f32_bf16(const float* __restrict__ s0,
                                                      const float* __restrict__ s1,
                                                      const float* __restrict__ s2,
                                                      u16* __restrict__ dst, long n4) {
  const float* src = (blockIdx.y == 0) ? s0 : ((blockIdx.y == 1) ? s1 : s2);
  long i = blockIdx.x * 256 + threadIdx.x;
  if (i >= n4) return;
  float4 f = ((const float4*)src)[i];
  u16x4 o;
  o.x = f2b(f.x); o.y = f2b(f.y); o.z = f2b(f.z); o.w = f2b(f.w);
  ((u16x4*)(dst + blockIdx.y * n4 * 4))[i] = o;
}

// ---------------- W[E,A] fp32 -> Wt[A,E] bf16, 3 weights in one launch ----------------
__global__ __launch_bounds__(256) void transpose_cast_w3(const float* __restrict__ w0,
                                                         const float* __restrict__ w1,
                                                         const float* __restrict__ w2,
                                                         u16* __restrict__ Wt, int E_, int A_) {
  __shared__ float tile[32][33];
  const float* W = (blockIdx.z == 0) ? w0 : ((blockIdx.z == 1) ? w1 : w2);
  u16* dst = Wt + (long)blockIdx.z * E_ * A_;
  int a0 = blockIdx.x * 32, e0 = blockIdx.y * 32;
  int tx = threadIdx.x & 31, ty = threadIdx.x >> 5;
  for (int i = ty; i < 32; i += 8) tile[i][tx] = W[(long)(e0 + i) * A_ + a0 + tx];
  __syncthreads();
  for (int i = ty; i < 32; i += 8) dst[(long)(a0 + i) * E_ + e0 + tx] = f2b(tile[tx][i]);
}

// ---------------- bf16 [rows,cols] -> [cols,rows], 64x64 tiles, u16x4 vectorized ----------------
__global__ __launch_bounds__(256) void transpose_bf16_64(const u16* __restrict__ src,
                                                         u16* __restrict__ dst, int rows, int cols) {
  __shared__ u16 tile[64][68];
  long bo = (long)blockIdx.z * rows * cols;
  int c0 = blockIdx.x * 64, r0 = blockIdx.y * 64;
  int t = threadIdx.x;
  int tx = t & 15, ty = t >> 4;
  for (int i = ty; i < 64; i += 16) {
    u16x4 v = *(const u16x4*)(src + bo + (long)(r0 + i) * cols + c0 + tx * 4);
    *(u16x4*)(&tile[i][tx * 4]) = v;
  }
  __syncthreads();
  for (int i = ty; i < 64; i += 16) {
    u16x4 o;
    o.x = tile[tx * 4 + 0][i];
    o.y = tile[tx * 4 + 1][i];
    o.z = tile[tx * 4 + 2][i];
    o.w = tile[tx * 4 + 3][i];
    *(u16x4*)(dst + bo + (long)(c0 + i) * rows + r0 + tx * 4) = o;
  }
}

// ---------------- bf16 MFMA GEMM: C[M,N] = A[M,K] * B[N,K]^T * scale + bias ----------------
// 128x128 tile, 4 waves of 64x64, BK=32, global_load_lds width=16 staging (m97 structure).
// Per-z bias select (for merged QKV projections). OUT_BF16 selects u16 vs f32 output.
template<bool OUT_BF16>
__global__ __launch_bounds__(256)
void gemm_bt(const u16* __restrict__ Ag, const u16* __restrict__ Bg,
             const float* __restrict__ b0, const float* __restrict__ b1,
             const float* __restrict__ b2, void* __restrict__ Cg,
             int M, int N, int K, float scale, long sA, long sB, long sC) {
  __shared__ u16 As[128 * 32];
  __shared__ u16 Bs[128 * 32];
  const int t = threadIdx.x;
  const int wave = t >> 6, lane = t & 63;
  const int quad = lane >> 4, l16 = lane & 15;
  const int wm = wave & 1, wn = wave >> 1;
  const int m0 = blockIdx.y * 128, n0 = blockIdx.x * 128;
  const int z = blockIdx.z;
  const float* bias = (z == 0) ? b0 : ((z == 1) ? b1 : b2);
  const long zA = (long)z * sA;
  const long zB = (long)z * sB;
  const long zC = (long)z * sC;

  // staging: thread t loads 8 bf16 (16B); row = t/4, col = (t%4)*8; LDS dest byte = t*16
  const int ar = t >> 2, ac = (t & 3) * 8;
  const u16* Ap0 = Ag + zA + (long)(m0 + ar) * K + ac;
  const u16* Ap1 = Ag + zA + (long)(m0 + 64 + ar) * K + ac;
  const u16* Bp0 = Bg + zB + (long)(n0 + ar) * K + ac;
  const u16* Bp1 = Bg + zB + (long)(n0 + 64 + ar) * K + ac;
  u16* AsD0 = As + wave * 512;        // wave-uniform LDS bases (bytes: wave*1024)
  u16* AsD1 = As + 2048 + wave * 512; // second half-tile at byte 4096
  u16* BsD0 = Bs + wave * 512;
  u16* BsD1 = Bs + 2048 + wave * 512;

  f32x4 acc[4][4] = {};

  // fragment read base: A[m=l16][k=quad*8+j], row stride 32 elems
  const u16* Ard = As + (wm * 64 + l16) * 32 + quad * 8;
  const u16* Brd = Bs + (wn * 64 + l16) * 32 + quad * 8;

  for (int k0 = 0; k0 < K; k0 += 32) {
    __builtin_amdgcn_global_load_lds(
        (const __attribute__((address_space(1))) unsigned int*)(Ap0 + k0),
        (__attribute__((address_space(3))) unsigned int*)AsD0, 16, 0, 0);
    __builtin_amdgcn_global_load_lds(
        (const __attribute__((address_space(1))) unsigned int*)(Ap1 + k0),
        (__attribute__((address_space(3))) unsigned int*)AsD1, 16, 0, 0);
    __builtin_amdgcn_global_load_lds(
        (const __attribute__((address_space(1))) unsigned int*)(Bp0 + k0),
        (__attribute__((address_space(3))) unsigned int*)BsD0, 16, 0, 0);
    __builtin_amdgcn_global_load_lds(
        (const __attribute__((address_space(1))) unsigned int*)(Bp1 + k0),
        (__attribute__((address_space(3))) unsigned int*)BsD1, 16, 0, 0);
    __syncthreads();

    s16x8 fa[4], fb[4];
#pragma unroll
    for (int i = 0; i < 4; i++) fa[i] = *(const s16x8*)(Ard + i * 512);
#pragma unroll
    for (int j = 0; j < 4; j++) fb[j] = *(const s16x8*)(Brd + j * 512);
#pragma unroll
    for (int i = 0; i < 4; i++)
#pragma unroll
      for (int j = 0; j < 4; j++)
        acc[i][j] = __builtin_amdgcn_mfma_f32_16x16x32_bf16(fa[i], fb[j], acc[i][j], 0, 0, 0);
    __syncthreads();
  }

  float bj[4];
#pragma unroll
  for (int j = 0; j < 4; j++) {
    int col = n0 + wn * 64 + j * 16 + l16;
    bj[j] = bias ? bias[col] : 0.0f;
  }
  // C/D layout (16x16x32 bf16): col = lane&15, row = quad*4 + reg
#pragma unroll
  for (int i = 0; i < 4; i++) {
#pragma unroll
    for (int r = 0; r < 4; r++) {
      long row = m0 + wm * 64 + i * 16 + quad * 4 + r;
      long ro = zC + row * (long)N;
#pragma unroll
      for (int j = 0; j < 4; j++) {
        int col = n0 + wn * 64 + j * 16 + l16;
        float v = acc[i][j][r] * scale + bj[j];
        if (OUT_BF16) ((u16*)Cg)[ro + col] = f2b(v);
        else          ((float*)Cg)[ro + col] = v;
      }
    }
  }
}

// ---------------- row softmax: bf16 [rows,2048] -> bf16 probs ----------------
__device__ __forceinline__ float wred_max(float x) {
  for (int o = 32; o > 0; o >>= 1) x = fmaxf(x, __shfl_xor(x, o));
  return x;
}
__device__ __forceinline__ float wred_sum(float x) {
  for (int o = 32; o > 0; o >>= 1) x += __shfl_xor(x, o);
  return x;
}

__global__ __launch_bounds__(256) void softmax_rows_bf16(const u16* __restrict__ S,
                                                         u16* __restrict__ P, int ncols) {
  long row = blockIdx.x;
  const u16x8* s8 = (const u16x8*)(S + row * (long)ncols);
  int t = threadIdx.x;
  int wave = t >> 6, lane = t & 63;
  u16x8 a = s8[t];
  float f[8];
#pragma unroll
  for (int i = 0; i < 8; i++) f[i] = b2f(a[i]);
  float m = f[0];
#pragma unroll
  for (int i = 1; i < 8; i++) m = fmaxf(m, f[i]);
  m = wred_max(m);
  __shared__ float redm[4], reds[4];
  if (lane == 0) redm[wave] = m;
  __syncthreads();
  m = fmaxf(fmaxf(redm[0], redm[1]), fmaxf(redm[2], redm[3]));

  float e[8], s = 0.f;
#pragma unroll
  for (int i = 0; i < 8; i++) { e[i] = __expf(f[i] - m); s += e[i]; }
  s = wred_sum(s);
  if (lane == 0) reds[wave] = s;
  __syncthreads();
  s = reds[0] + reds[1] + reds[2] + reds[3];
  float inv = 1.0f / s;

  u16x8 o;
#pragma unroll
  for (int i = 0; i < 8; i++) o[i] = f2b(e[i] * inv);
  ((u16x8*)(P + row * (long)ncols))[t] = o;
}

extern "C" void kernel_launch(void* const* d_in, const int* in_sizes, int n_in,
                              void* d_out, int out_size, void* d_ws, size_t ws_size,
                              hipStream_t stream) {
  const float* query = (const float*)d_in[0];
  const float* key_  = (const float*)d_in[1];
  const float* value = (const float*)d_in[2];
  const float* Wq = (const float*)d_in[3];
  const float* bq = (const float*)d_in[4];
  const float* Wk = (const float*)d_in[5];
  const float* bk = (const float*)d_in[6];
  const float* Wv = (const float*)d_in[7];
  const float* bv = (const float*)d_in[8];

  constexpr int B = 4, S = 2048, E = 1024, A = 1024;
  constexpr long MB = 1024 * 1024;
  char* ws = (char*)d_ws;
  // layout (MiB): Qb 0-16, Kb 16-32, Vb 32-48, Vt 48-64, P 64-96, Sc(bf16) 96-128.
  // transient bf16 casts X* at 96-144 are consumed by projections before Sc is written.
  // Wt (3 contiguous) at 144-150.
  u16* Qb  = (u16*)(ws + 0 * MB);   // also Kb at +16MB, Vb at +32MB (z-stride 8M elems)
  u16* Vt  = (u16*)(ws + 48 * MB);
  u16* P   = (u16*)(ws + 64 * MB);
  u16* Sc  = (u16*)(ws + 96 * MB);
  u16* Xq  = (u16*)(ws + 96 * MB);  // z-stride 8M elems (16 MB)
  u16* WqT = (u16*)(ws + 144 * MB); // z-stride 1M elems (2 MB)
  u16* Kb  = (u16*)(ws + 16 * MB);

  const long n = (long)B * S * E;   // 8M activation elements per tensor
  const long n4 = n / 4;
  dim3 blk(256);

  // 1) cast q/k/v fp32 -> bf16 (one launch)
  cast3_f32_bf16<<<dim3(n4 / 256, 3), blk, 0, stream>>>(query, key_, value, Xq, n4);

  // 2) W[E,A] -> Wt[A,E] bf16, all three (one launch)
  transpose_cast_w3<<<dim3(A / 32, E / 32, 3), blk, 0, stream>>>(Wq, Wk, Wv, WqT, E, A);

  // 3) merged QKV projections: z=0,1,2 -> Qb/Kb/Vb bf16. 1536 blocks.
  dim3 pg(A / 128, (B * S) / 128, 3);
  gemm_bt<true><<<pg, blk, 0, stream>>>(Xq, WqT, bq, bk, bv, Qb,
                                        B * S, A, E, 1.0f,
                                        (long)8 * MB, (long)1 * MB, (long)8 * MB);

  // 4) V^T for the PV gemm ([S,A] -> [A,S] per batch)
  transpose_bf16_64<<<dim3(A / 64, S / 64, B), blk, 0, stream>>>((u16*)(ws + 32 * MB), Vt, S, A);

  // 5) scores = Q K^T / sqrt(A) -> bf16, batched over B. 1024 blocks.
  dim3 sg(S / 128, S / 128, B);
  gemm_bt<true><<<sg, blk, 0, stream>>>(Qb, Kb, nullptr, nullptr, nullptr, Sc,
                                        S, S, A, 0.03125f,
                                        (long)S * A, (long)S * A, (long)S * S);

  // 6) softmax rows (bf16 in, bf16 out)
  softmax_rows_bf16<<<dim3(B * S), blk, 0, stream>>>(Sc, P, S);

  // 7) out = P V : A=P[S,S], B=Vt[A,S] -> fp32 d_out. 512 blocks.
  dim3 og(A / 128, S / 128, B);
  gemm_bt<false><<<og, blk, 0, stream>>>(P, Vt, nullptr, nullptr, nullptr, (float*)d_out,
                                         S, A, S, 1.0f,
                                         (long)S * S, (long)S * A, (long)S * A);
}

// Round 3
// 366.285 us; speedup vs baseline: 1.1197x; 1.0191x over previous
//
#include <hip/hip_runtime.h>

typedef unsigned short u16;
typedef __attribute__((ext_vector_type(4))) float f32x4;
typedef __attribute__((ext_vector_type(8))) short s16x8;
typedef __attribute__((ext_vector_type(8))) unsigned short u16x8;
typedef __attribute__((ext_vector_type(4))) unsigned short u16x4;

// round-to-nearest-even f32 -> bf16
__device__ __forceinline__ u16 f2b(float x) {
  union { float f; unsigned u; } v; v.f = x;
  unsigned r = v.u + 0x7fffu + ((v.u >> 16) & 1u);
  return (u16)(r >> 16);
}
__device__ __forceinline__ float b2f(u16 x) {
  union { unsigned u; float f; } v; v.u = ((unsigned)x) << 16;
  return v.f;
}

// ---------------- cast fp32 -> bf16, 3 inputs in one launch (grid.y selects) ----------------
__global__ __launch_bounds__(256) void cast3_f32_bf16(const float* __restrict__ s0,
                                                      const float* __restrict__ s1,
                                                      const float* __restrict__ s2,
                                                      u16* __restrict__ dst, long n4) {
  const float* src = (blockIdx.y == 0) ? s0 : ((blockIdx.y == 1) ? s1 : s2);
  long i = blockIdx.x * 256 + threadIdx.x;
  if (i >= n4) return;
  float4 f = ((const float4*)src)[i];
  u16x4 o;
  o.x = f2b(f.x); o.y = f2b(f.y); o.z = f2b(f.z); o.w = f2b(f.w);
  ((u16x4*)(dst + blockIdx.y * n4 * 4))[i] = o;
}

// ---------------- W[E,A] fp32 -> Wt[A,E] bf16, 3 weights in one launch ----------------
__global__ __launch_bounds__(256) void transpose_cast_w3(const float* __restrict__ w0,
                                                         const float* __restrict__ w1,
                                                         const float* __restrict__ w2,
                                                         u16* __restrict__ Wt, int E_, int A_) {
  __shared__ float tile[32][33];
  const float* W = (blockIdx.z == 0) ? w0 : ((blockIdx.z == 1) ? w1 : w2);
  u16* dst = Wt + (long)blockIdx.z * E_ * A_;
  int a0 = blockIdx.x * 32, e0 = blockIdx.y * 32;
  int tx = threadIdx.x & 31, ty = threadIdx.x >> 5;
  for (int i = ty; i < 32; i += 8) tile[i][tx] = W[(long)(e0 + i) * A_ + a0 + tx];
  __syncthreads();
  for (int i = ty; i < 32; i += 8) dst[(long)(a0 + i) * E_ + e0 + tx] = f2b(tile[tx][i]);
}

// ---------------- bf16 MFMA GEMM: C[M,N] = A[M,K] * B[N,K]^T * scale + bias ----------------
// 128x128 tile, 4 waves of 64x64, BK=32, global_load_lds width=16 staging (m97 structure).
// XCD-aware swizzle: linear block id L -> XCD c = L%8 owns an (XM x XN)-th of the tile
// grid, sized so its A-band + B-band working set fits the 4 MB per-XCD L2.
// Optional: z==2 writes output TRANSPOSED into VtG (bf16 scatter) for the PV gemm.
template<bool OUT_BF16>
__global__ __launch_bounds__(256)
void gemm_bt(const u16* __restrict__ Ag, const u16* __restrict__ Bg,
             const float* __restrict__ b0, const float* __restrict__ b1,
             const float* __restrict__ b2, void* __restrict__ Cg,
             int M, int N, int K, float scale, long sA, long sB, long sC,
             int XM, int XN, u16* __restrict__ VtG, long vtB, int vtS) {
  __shared__ u16 As[128 * 32];
  __shared__ u16 Bs[128 * 32];
  const int t = threadIdx.x;
  const int wave = t >> 6, lane = t & 63;
  const int quad = lane >> 4, l16 = lane & 15;
  const int wm = wave & 1, wn = wave >> 1;

  // XCD swizzle: c = L % 8 is the XCD (dispatch round-robin heuristic).
  const int gn = gridDim.x, gm = gridDim.y;
  const int L = blockIdx.y * gn + blockIdx.x;
  const int c = L & 7, tt = L >> 3;
  const int sm = gm / XM, sn = gn / XN;
  const int cm = c % XM, cn = c / XM;
  const int tm = tt % sm, tn = tt / sm;
  const int m0 = (cm * sm + tm) * 128;
  const int n0 = (cn * sn + tn) * 128;

  const int z = blockIdx.z;
  const float* bias = (z == 0) ? b0 : ((z == 1) ? b1 : b2);
  const long zA = (long)z * sA;
  const long zB = (long)z * sB;
  const long zC = (long)z * sC;

  // staging: thread t loads 8 bf16 (16B); row = t/4, col = (t%4)*8; LDS dest byte = t*16
  const int ar = t >> 2, ac = (t & 3) * 8;
  const u16* Ap0 = Ag + zA + (long)(m0 + ar) * K + ac;
  const u16* Ap1 = Ag + zA + (long)(m0 + 64 + ar) * K + ac;
  const u16* Bp0 = Bg + zB + (long)(n0 + ar) * K + ac;
  const u16* Bp1 = Bg + zB + (long)(n0 + 64 + ar) * K + ac;
  u16* AsD0 = As + wave * 512;        // wave-uniform LDS bases (bytes: wave*1024)
  u16* AsD1 = As + 2048 + wave * 512; // second half-tile at byte 4096
  u16* BsD0 = Bs + wave * 512;
  u16* BsD1 = Bs + 2048 + wave * 512;

  f32x4 acc[4][4] = {};

  // fragment read base: A[m=l16][k=quad*8+j], row stride 32 elems
  const u16* Ard = As + (wm * 64 + l16) * 32 + quad * 8;
  const u16* Brd = Bs + (wn * 64 + l16) * 32 + quad * 8;

  for (int k0 = 0; k0 < K; k0 += 32) {
    __builtin_amdgcn_global_load_lds(
        (const __attribute__((address_space(1))) unsigned int*)(Ap0 + k0),
        (__attribute__((address_space(3))) unsigned int*)AsD0, 16, 0, 0);
    __builtin_amdgcn_global_load_lds(
        (const __attribute__((address_space(1))) unsigned int*)(Ap1 + k0),
        (__attribute__((address_space(3))) unsigned int*)AsD1, 16, 0, 0);
    __builtin_amdgcn_global_load_lds(
        (const __attribute__((address_space(1))) unsigned int*)(Bp0 + k0),
        (__attribute__((address_space(3))) unsigned int*)BsD0, 16, 0, 0);
    __builtin_amdgcn_global_load_lds(
        (const __attribute__((address_space(1))) unsigned int*)(Bp1 + k0),
        (__attribute__((address_space(3))) unsigned int*)BsD1, 16, 0, 0);
    __syncthreads();

    s16x8 fa[4], fb[4];
#pragma unroll
    for (int i = 0; i < 4; i++) fa[i] = *(const s16x8*)(Ard + i * 512);
#pragma unroll
    for (int j = 0; j < 4; j++) fb[j] = *(const s16x8*)(Brd + j * 512);
#pragma unroll
    for (int i = 0; i < 4; i++)
#pragma unroll
      for (int j = 0; j < 4; j++)
        acc[i][j] = __builtin_amdgcn_mfma_f32_16x16x32_bf16(fa[i], fb[j], acc[i][j], 0, 0, 0);
    __syncthreads();
  }

  float bj[4];
#pragma unroll
  for (int j = 0; j < 4; j++) {
    int col = n0 + wn * 64 + j * 16 + l16;
    bj[j] = bias ? bias[col] : 0.0f;
  }

  // C/D layout (16x16x32 bf16): col = lane&15, row = quad*4 + reg
  if (OUT_BF16 && VtG != nullptr && z == 2) {
    // transposed scatter: Vt[b][col][s] = C[row][col]; same 16 store insts, strided.
    const int b = m0 / (vtS);           // m0 is batch*vtS aligned to 128 | vtS
    const int smod = m0 % vtS;
    u16* vbase = VtG + (long)b * vtB + smod;
#pragma unroll
    for (int i = 0; i < 4; i++) {
#pragma unroll
      for (int r = 0; r < 4; r++) {
        int row = wm * 64 + i * 16 + quad * 4 + r;
#pragma unroll
        for (int j = 0; j < 4; j++) {
          int col = n0 + wn * 64 + j * 16 + l16;
          vbase[(long)col * vtS + row] = f2b(acc[i][j][r] * scale + bj[j]);
        }
      }
    }
  } else {
#pragma unroll
    for (int i = 0; i < 4; i++) {
#pragma unroll
      for (int r = 0; r < 4; r++) {
        long row = m0 + wm * 64 + i * 16 + quad * 4 + r;
        long ro = zC + row * (long)N;
#pragma unroll
        for (int j = 0; j < 4; j++) {
          int col = n0 + wn * 64 + j * 16 + l16;
          float v = acc[i][j][r] * scale + bj[j];
          if (OUT_BF16) ((u16*)Cg)[ro + col] = f2b(v);
          else          ((float*)Cg)[ro + col] = v;
        }
      }
    }
  }
}

// ---------------- row softmax: bf16 [rows,2048] -> bf16 probs ----------------
__device__ __forceinline__ float wred_max(float x) {
  for (int o = 32; o > 0; o >>= 1) x = fmaxf(x, __shfl_xor(x, o));
  return x;
}
__device__ __forceinline__ float wred_sum(float x) {
  for (int o = 32; o > 0; o >>= 1) x += __shfl_xor(x, o);
  return x;
}

__global__ __launch_bounds__(256) void softmax_rows_bf16(const u16* __restrict__ S,
                                                         u16* __restrict__ P, int ncols) {
  long row = blockIdx.x;
  const u16x8* s8 = (const u16x8*)(S + row * (long)ncols);
  int t = threadIdx.x;
  int wave = t >> 6, lane = t & 63;
  u16x8 a = s8[t];
  float f[8];
#pragma unroll
  for (int i = 0; i < 8; i++) f[i] = b2f(a[i]);
  float m = f[0];
#pragma unroll
  for (int i = 1; i < 8; i++) m = fmaxf(m, f[i]);
  m = wred_max(m);
  __shared__ float redm[4], reds[4];
  if (lane == 0) redm[wave] = m;
  __syncthreads();
  m = fmaxf(fmaxf(redm[0], redm[1]), fmaxf(redm[2], redm[3]));

  float e[8], s = 0.f;
#pragma unroll
  for (int i = 0; i < 8; i++) { e[i] = __expf(f[i] - m); s += e[i]; }
  s = wred_sum(s);
  if (lane == 0) reds[wave] = s;
  __syncthreads();
  s = reds[0] + reds[1] + reds[2] + reds[3];
  float inv = 1.0f / s;

  u16x8 o;
#pragma unroll
  for (int i = 0; i < 8; i++) o[i] = f2b(e[i] * inv);
  ((u16x8*)(P + row * (long)ncols))[t] = o;
}

extern "C" void kernel_launch(void* const* d_in, const int* in_sizes, int n_in,
                              void* d_out, int out_size, void* d_ws, size_t ws_size,
                              hipStream_t stream) {
  const float* query = (const float*)d_in[0];
  const float* key_  = (const float*)d_in[1];
  const float* value = (const float*)d_in[2];
  const float* Wq = (const float*)d_in[3];
  const float* bq = (const float*)d_in[4];
  const float* Wk = (const float*)d_in[5];
  const float* bk = (const float*)d_in[6];
  const float* Wv = (const float*)d_in[7];
  const float* bv = (const float*)d_in[8];

  constexpr int B = 4, S = 2048, E = 1024, A = 1024;
  constexpr long MB = 1024 * 1024;
  char* ws = (char*)d_ws;
  // layout (MiB): Qb 0-16, Kb 16-32, (unused 32-48), Vt 48-64, P 64-96, Sc(bf16) 96-128.
  // transient bf16 casts X* at 96-144 are consumed by projections before Sc is written.
  // Wt (3 contiguous) at 144-150.
  u16* Qb  = (u16*)(ws + 0 * MB);
  u16* Kb  = (u16*)(ws + 16 * MB);
  u16* Vt  = (u16*)(ws + 48 * MB);
  u16* P   = (u16*)(ws + 64 * MB);
  u16* Sc  = (u16*)(ws + 96 * MB);
  u16* Xq  = (u16*)(ws + 96 * MB);  // z-stride 8M elems (16 MB)
  u16* WqT = (u16*)(ws + 144 * MB); // z-stride 1M elems (2 MB)

  const long n = (long)B * S * E;   // 8M activation elements per tensor
  const long n4 = n / 4;
  dim3 blk(256);

  // 1) cast q/k/v fp32 -> bf16 (one launch)
  cast3_f32_bf16<<<dim3(n4 / 256, 3), blk, 0, stream>>>(query, key_, value, Xq, n4);

  // 2) W[E,A] -> Wt[A,E] bf16, all three (one launch)
  transpose_cast_w3<<<dim3(A / 32, E / 32, 3), blk, 0, stream>>>(Wq, Wk, Wv, WqT, E, A);

  // 3) merged QKV projections: z=0->Qb, z=1->Kb, z=2->Vt (transposed scatter).
  //    grid per z: 8n x 64m. XM=8,XN=1: XCD c gets m-band of 8 tiles (2MB A) + all W (2MB).
  dim3 pg(A / 128, (B * S) / 128, 3);
  gemm_bt<true><<<pg, blk, 0, stream>>>(Xq, WqT, bq, bk, bv, Qb,
                                        B * S, A, E, 1.0f,
                                        (long)8 * MB, (long)1 * MB, (long)8 * MB,
                                        8, 1, Vt, (long)A * S, S);

  // 4) scores = Q K^T / sqrt(A) -> bf16, batched over B. grid per z: 16n x 16m.
  //    XM=4,XN=2: XCD gets 4m (1MB Q) x 8n (2MB K).
  dim3 sg(S / 128, S / 128, B);
  gemm_bt<true><<<sg, blk, 0, stream>>>(Qb, Kb, nullptr, nullptr, nullptr, Sc,
                                        S, S, A, 0.03125f,
                                        (long)S * A, (long)S * A, (long)S * S,
                                        4, 2, nullptr, 0, 0);

  // 5) softmax rows (bf16 in, bf16 out)
  softmax_rows_bf16<<<dim3(B * S), blk, 0, stream>>>(Sc, P, S);

  // 6) out = P V : A=P[S,S], B=Vt[A,S] -> fp32 d_out. grid per z: 8n x 16m.
  //    XM=4,XN=2: XCD gets 4m (2MB P) x 4n (2MB Vt).
  dim3 og(A / 128, S / 128, B);
  gemm_bt<false><<<og, blk, 0, stream>>>(P, Vt, nullptr, nullptr, nullptr, (float*)d_out,
                                         S, A, S, 1.0f,
                                         (long)S * S, (long)S * A, (long)S * A,
                                         4, 2, nullptr, 0, 0);
}

// Round 4
// 360.522 us; speedup vs baseline: 1.1376x; 1.0160x over previous
//
#include <hip/hip_runtime.h>

typedef unsigned short u16;
typedef __attribute__((ext_vector_type(16))) float f32x16;
typedef __attribute__((ext_vector_type(8))) short s16x8;
typedef __attribute__((ext_vector_type(8))) unsigned short u16x8;
typedef __attribute__((ext_vector_type(4))) unsigned short u16x4;

// round-to-nearest-even f32 -> bf16
__device__ __forceinline__ u16 f2b(float x) {
  union { float f; unsigned u; } v; v.f = x;
  unsigned r = v.u + 0x7fffu + ((v.u >> 16) & 1u);
  return (u16)(r >> 16);
}
__device__ __forceinline__ float b2f(u16 x) {
  union { unsigned u; float f; } v; v.u = ((unsigned)x) << 16;
  return v.f;
}

// ---------------- cast fp32 -> bf16, 3 inputs in one launch (grid.y selects) ----------------
__global__ __launch_bounds__(256) void cast3_f32_bf16(const float* __restrict__ s0,
                                                      const float* __restrict__ s1,
                                                      const float* __restrict__ s2,
                                                      u16* __restrict__ dst, long n4) {
  const float* src = (blockIdx.y == 0) ? s0 : ((blockIdx.y == 1) ? s1 : s2);
  long i = blockIdx.x * 256 + threadIdx.x;
  if (i >= n4) return;
  float4 f = ((const float4*)src)[i];
  u16x4 o;
  o.x = f2b(f.x); o.y = f2b(f.y); o.z = f2b(f.z); o.w = f2b(f.w);
  ((u16x4*)(dst + blockIdx.y * n4 * 4))[i] = o;
}

// ---------------- W[E,A] fp32 -> Wt[A,E] bf16, 3 weights in one launch ----------------
__global__ __launch_bounds__(256) void transpose_cast_w3(const float* __restrict__ w0,
                                                         const float* __restrict__ w1,
                                                         const float* __restrict__ w2,
                                                         u16* __restrict__ Wt, int E_, int A_) {
  __shared__ float tile[32][33];
  const float* W = (blockIdx.z == 0) ? w0 : ((blockIdx.z == 1) ? w1 : w2);
  u16* dst = Wt + (long)blockIdx.z * E_ * A_;
  int a0 = blockIdx.x * 32, e0 = blockIdx.y * 32;
  int tx = threadIdx.x & 31, ty = threadIdx.x >> 5;
  for (int i = ty; i < 32; i += 8) tile[i][tx] = W[(long)(e0 + i) * A_ + a0 + tx];
  __syncthreads();
  for (int i = ty; i < 32; i += 8) dst[(long)(a0 + i) * E_ + e0 + tx] = f2b(tile[tx][i]);
}

// ---------------- bf16 MFMA GEMM: C[M,N] = A[M,K] * B[N,K]^T * scale + bias ----------------
// 128x128 tile, 4 waves of 64x64, BK=32, global_load_lds width=16 staging (m97 structure),
// 32x32x16 bf16 MFMA inner loop (8 MFMA/iter vs 16 for the 16x16 shape).
// XCD-aware swizzle: linear block id L -> XCD c = L%8 owns an (XM x XN)-th of the grid.
// z==2 optionally writes output TRANSPOSED into VtG via 8-B u16x4 stores (regs r..r+3
// are consecutive rows in the 32x32 C/D layout).
template<bool OUT_BF16>
__global__ __launch_bounds__(256)
void gemm_bt(const u16* __restrict__ Ag, const u16* __restrict__ Bg,
             const float* __restrict__ b0, const float* __restrict__ b1,
             const float* __restrict__ b2, void* __restrict__ Cg,
             int M, int N, int K, float scale, long sA, long sB, long sC,
             int XM, int XN, u16* __restrict__ VtG, long vtB, int vtS) {
  __shared__ u16 As[128 * 32];
  __shared__ u16 Bs[128 * 32];
  const int t = threadIdx.x;
  const int wave = t >> 6, lane = t & 63;
  const int l32 = lane & 31, hi = lane >> 5;
  const int wm = wave & 1, wn = wave >> 1;

  // XCD swizzle: c = L % 8 is the XCD (dispatch round-robin heuristic).
  const int gn = gridDim.x, gm = gridDim.y;
  const int L = blockIdx.y * gn + blockIdx.x;
  const int c = L & 7, tt = L >> 3;
  const int sm = gm / XM, sn = gn / XN;
  const int cm = c % XM, cn = c / XM;
  const int tm = tt % sm, tn = tt / sm;
  const int m0 = (cm * sm + tm) * 128;
  const int n0 = (cn * sn + tn) * 128;

  const int z = blockIdx.z;
  const float* bias = (z == 0) ? b0 : ((z == 1) ? b1 : b2);
  const long zA = (long)z * sA;
  const long zB = (long)z * sB;
  const long zC = (long)z * sC;

  // staging: thread t loads 8 bf16 (16B); row = t/4, col = (t%4)*8; LDS dest byte = t*16
  const int ar = t >> 2, ac = (t & 3) * 8;
  const u16* Ap0 = Ag + zA + (long)(m0 + ar) * K + ac;
  const u16* Ap1 = Ag + zA + (long)(m0 + 64 + ar) * K + ac;
  const u16* Bp0 = Bg + zB + (long)(n0 + ar) * K + ac;
  const u16* Bp1 = Bg + zB + (long)(n0 + 64 + ar) * K + ac;
  u16* AsD0 = As + wave * 512;        // wave-uniform LDS bases (bytes: wave*1024)
  u16* AsD1 = As + 2048 + wave * 512; // second half-tile at byte 4096
  u16* BsD0 = Bs + wave * 512;
  u16* BsD1 = Bs + 2048 + wave * 512;

  f32x16 acc[2][2] = {};

  // 32x32x16 A/B fragment: lane holds [m|n = l32][k = hi*8 + 0..7], 16 B contiguous.
  // As is [128 rows][32 k]: elem = row*32 + kk*16 + hi*8.
  const u16* Ard = As + (wm * 64 + l32) * 32 + hi * 8;
  const u16* Brd = Bs + (wn * 64 + l32) * 32 + hi * 8;

  for (int k0 = 0; k0 < K; k0 += 32) {
    __builtin_amdgcn_global_load_lds(
        (const __attribute__((address_space(1))) unsigned int*)(Ap0 + k0),
        (__attribute__((address_space(3))) unsigned int*)AsD0, 16, 0, 0);
    __builtin_amdgcn_global_load_lds(
        (const __attribute__((address_space(1))) unsigned int*)(Ap1 + k0),
        (__attribute__((address_space(3))) unsigned int*)AsD1, 16, 0, 0);
    __builtin_amdgcn_global_load_lds(
        (const __attribute__((address_space(1))) unsigned int*)(Bp0 + k0),
        (__attribute__((address_space(3))) unsigned int*)BsD0, 16, 0, 0);
    __builtin_amdgcn_global_load_lds(
        (const __attribute__((address_space(1))) unsigned int*)(Bp1 + k0),
        (__attribute__((address_space(3))) unsigned int*)BsD1, 16, 0, 0);
    __syncthreads();

    s16x8 fa[2][2], fb[2][2];   // [i or j][kk]
#pragma unroll
    for (int i = 0; i < 2; i++)
#pragma unroll
      for (int kk = 0; kk < 2; kk++) {
        fa[i][kk] = *(const s16x8*)(Ard + i * 1024 + kk * 16);
        fb[i][kk] = *(const s16x8*)(Brd + i * 1024 + kk * 16);
      }
#pragma unroll
    for (int kk = 0; kk < 2; kk++)
#pragma unroll
      for (int i = 0; i < 2; i++)
#pragma unroll
        for (int j = 0; j < 2; j++)
          acc[i][j] = __builtin_amdgcn_mfma_f32_32x32x16_bf16(fa[i][kk], fb[j][kk],
                                                              acc[i][j], 0, 0, 0);
    __syncthreads();
  }

  float bj[2];
#pragma unroll
  for (int j = 0; j < 2; j++) {
    int col = n0 + wn * 64 + j * 32 + l32;
    bj[j] = bias ? bias[col] : 0.0f;
  }

  // 32x32 C/D layout: col = l32, row = (r&3) + 8*(r>>2) + 4*hi  (m74/m101-verified)
  if (OUT_BF16 && VtG != nullptr && z == 2) {
    // transposed scatter into Vt[b][col][s]: regs g*4..g*4+3 are 4 consecutive s -> u16x4.
    const int b = m0 / vtS;
    const int smod = m0 % vtS;
    u16* vbase = VtG + (long)b * vtB + smod;
#pragma unroll
    for (int i = 0; i < 2; i++)
#pragma unroll
      for (int j = 0; j < 2; j++) {
        int col = n0 + wn * 64 + j * 32 + l32;
        u16* cb = vbase + (long)col * vtS + wm * 64 + i * 32 + 4 * hi;
#pragma unroll
        for (int g = 0; g < 4; g++) {
          u16x4 o;
#pragma unroll
          for (int rr = 0; rr < 4; rr++) o[rr] = f2b(acc[i][j][g * 4 + rr] * scale + bj[j]);
          *(u16x4*)(cb + g * 8) = o;
        }
      }
  } else {
#pragma unroll
    for (int i = 0; i < 2; i++)
#pragma unroll
      for (int j = 0; j < 2; j++) {
        int col = n0 + wn * 64 + j * 32 + l32;
#pragma unroll
        for (int r = 0; r < 16; r++) {
          long row = m0 + wm * 64 + i * 32 + (r & 3) + 8 * (r >> 2) + 4 * hi;
          float v = acc[i][j][r] * scale + bj[j];
          long ro = zC + row * (long)N + col;
          if (OUT_BF16) ((u16*)Cg)[ro] = f2b(v);
          else          ((float*)Cg)[ro] = v;
        }
      }
  }
}

// ---------------- row softmax: bf16 [rows,2048] -> bf16 probs ----------------
__device__ __forceinline__ float wred_max(float x) {
  for (int o = 32; o > 0; o >>= 1) x = fmaxf(x, __shfl_xor(x, o));
  return x;
}
__device__ __forceinline__ float wred_sum(float x) {
  for (int o = 32; o > 0; o >>= 1) x += __shfl_xor(x, o);
  return x;
}

__global__ __launch_bounds__(256) void softmax_rows_bf16(const u16* __restrict__ S,
                                                         u16* __restrict__ P, int ncols) {
  long row = blockIdx.x;
  const u16x8* s8 = (const u16x8*)(S + row * (long)ncols);
  int t = threadIdx.x;
  int wave = t >> 6, lane = t & 63;
  u16x8 a = s8[t];
  float f[8];
#pragma unroll
  for (int i = 0; i < 8; i++) f[i] = b2f(a[i]);
  float m = f[0];
#pragma unroll
  for (int i = 1; i < 8; i++) m = fmaxf(m, f[i]);
  m = wred_max(m);
  __shared__ float redm[4], reds[4];
  if (lane == 0) redm[wave] = m;
  __syncthreads();
  m = fmaxf(fmaxf(redm[0], redm[1]), fmaxf(redm[2], redm[3]));

  float e[8], s = 0.f;
#pragma unroll
  for (int i = 0; i < 8; i++) { e[i] = __expf(f[i] - m); s += e[i]; }
  s = wred_sum(s);
  if (lane == 0) reds[wave] = s;
  __syncthreads();
  s = reds[0] + reds[1] + reds[2] + reds[3];
  float inv = 1.0f / s;

  u16x8 o;
#pragma unroll
  for (int i = 0; i < 8; i++) o[i] = f2b(e[i] * inv);
  ((u16x8*)(P + row * (long)ncols))[t] = o;
}

extern "C" void kernel_launch(void* const* d_in, const int* in_sizes, int n_in,
                              void* d_out, int out_size, void* d_ws, size_t ws_size,
                              hipStream_t stream) {
  const float* query = (const float*)d_in[0];
  const float* key_  = (const float*)d_in[1];
  const float* value = (const float*)d_in[2];
  const float* Wq = (const float*)d_in[3];
  const float* bq = (const float*)d_in[4];
  const float* Wk = (const float*)d_in[5];
  const float* bk = (const float*)d_in[6];
  const float* Wv = (const float*)d_in[7];
  const float* bv = (const float*)d_in[8];

  constexpr int B = 4, S = 2048, E = 1024, A = 1024;
  constexpr long MB = 1024 * 1024;
  char* ws = (char*)d_ws;
  // layout (MiB): Qb 0-16, Kb 16-32, (unused 32-48), Vt 48-64, P 64-96, Sc(bf16) 96-128.
  // transient bf16 casts X* at 96-144 are consumed by projections before Sc is written.
  // Wt (3 contiguous) at 144-150.
  u16* Qb  = (u16*)(ws + 0 * MB);
  u16* Kb  = (u16*)(ws + 16 * MB);
  u16* Vt  = (u16*)(ws + 48 * MB);
  u16* P   = (u16*)(ws + 64 * MB);
  u16* Sc  = (u16*)(ws + 96 * MB);
  u16* Xq  = (u16*)(ws + 96 * MB);  // z-stride 8M elems (16 MB)
  u16* WqT = (u16*)(ws + 144 * MB); // z-stride 1M elems (2 MB)

  const long n = (long)B * S * E;   // 8M activation elements per tensor
  const long n4 = n / 4;
  dim3 blk(256);

  // 1) cast q/k/v fp32 -> bf16 (one launch)
  cast3_f32_bf16<<<dim3(n4 / 256, 3), blk, 0, stream>>>(query, key_, value, Xq, n4);

  // 2) W[E,A] -> Wt[A,E] bf16, all three (one launch)
  transpose_cast_w3<<<dim3(A / 32, E / 32, 3), blk, 0, stream>>>(Wq, Wk, Wv, WqT, E, A);

  // 3) merged QKV projections: z=0->Qb, z=1->Kb, z=2->Vt (transposed u16x4 scatter).
  dim3 pg(A / 128, (B * S) / 128, 3);
  gemm_bt<true><<<pg, blk, 0, stream>>>(Xq, WqT, bq, bk, bv, Qb,
                                        B * S, A, E, 1.0f,
                                        (long)8 * MB, (long)1 * MB, (long)8 * MB,
                                        8, 1, Vt, (long)A * S, S);

  // 4) scores = Q K^T / sqrt(A) -> bf16, batched over B. XM=4,XN=2.
  dim3 sg(S / 128, S / 128, B);
  gemm_bt<true><<<sg, blk, 0, stream>>>(Qb, Kb, nullptr, nullptr, nullptr, Sc,
                                        S, S, A, 0.03125f,
                                        (long)S * A, (long)S * A, (long)S * S,
                                        4, 2, nullptr, 0, 0);

  // 5) softmax rows (bf16 in, bf16 out)
  softmax_rows_bf16<<<dim3(B * S), blk, 0, stream>>>(Sc, P, S);

  // 6) out = P V : A=P[S,S], B=Vt[A,S] -> fp32 d_out. XM=4,XN=2.
  dim3 og(A / 128, S / 128, B);
  gemm_bt<false><<<og, blk, 0, stream>>>(P, Vt, nullptr, nullptr, nullptr, (float*)d_out,
                                         S, A, S, 1.0f,
                                         (long)S * S, (long)S * A, (long)S * A,
                                         4, 2, nullptr, 0, 0);
}